// Round 1
// baseline (3584.949 us; speedup 1.0000x reference)
//
#include <hip/hip_runtime.h>
#include <cstddef>

#define Bsz 16
#define Ssz 1024
#define Dsz 1024
#define Hn  16
#define HDs 64
#define SCALE_F 0.125f

// ---------------------------------------------------------------------------
// C[M,N] = A[M,K] @ W[K,N] + bias[N]   (fp32, 64x64 tile, 4x4 per thread)
// ---------------------------------------------------------------------------
__global__ __launch_bounds__(256) void gemm_bias_k(
    const float* __restrict__ A, const float* __restrict__ W,
    const float* __restrict__ bias, float* __restrict__ C,
    int M, int N, int K)
{
    __shared__ float As[64][17];   // [m][k]  pad->17 so 4 tr-rows hit 4 banks
    __shared__ float Bs[16][64];   // [k][n]

    const int tid = threadIdx.x;
    const int bm = blockIdx.y * 64;
    const int bn = blockIdx.x * 64;
    const int tr = tid >> 4;            // 0..15
    const int tc = tid & 15;            // 0..15

    const int lm  = tid >> 2;           // 0..63   A tile row
    const int lk4 = (tid & 3) << 2;     // 0,4,8,12
    const int lkb = tid >> 4;           // 0..15   B tile k-row
    const int lnb = (tid & 15) << 2;    // col*4

    float acc[4][4] = {};

    for (int k0 = 0; k0 < K; k0 += 16) {
        float4 a4 = *(const float4*)&A[(size_t)(bm + lm) * K + k0 + lk4];
        As[lm][lk4 + 0] = a4.x; As[lm][lk4 + 1] = a4.y;
        As[lm][lk4 + 2] = a4.z; As[lm][lk4 + 3] = a4.w;
        *(float4*)&Bs[lkb][lnb] = *(const float4*)&W[(size_t)(k0 + lkb) * N + bn + lnb];
        __syncthreads();
        #pragma unroll
        for (int kk = 0; kk < 16; ++kk) {
            float a[4], b[4];
            #pragma unroll
            for (int i = 0; i < 4; ++i) a[i] = As[tr * 4 + i][kk];
            #pragma unroll
            for (int j = 0; j < 4; ++j) b[j] = Bs[kk][tc * 4 + j];
            #pragma unroll
            for (int i = 0; i < 4; ++i)
                #pragma unroll
                for (int j = 0; j < 4; ++j)
                    acc[i][j] += a[i] * b[j];
        }
        __syncthreads();
    }

    #pragma unroll
    for (int i = 0; i < 4; ++i) {
        const int row = bm + tr * 4 + i;
        #pragma unroll
        for (int j = 0; j < 4; ++j) {
            const int col = bn + tc * 4 + j;
            C[(size_t)row * N + col] = acc[i][j] + bias[col];
        }
    }
}

// ---------------------------------------------------------------------------
// scores[b,h,q,k] = SCALE * sum_d Q[b,q,h*64+d] * K[b,k,h*64+d]
// one block -> 64x64 score tile of one (b,h)
// ---------------------------------------------------------------------------
__global__ __launch_bounds__(256) void scores_k(
    const float* __restrict__ Q, const float* __restrict__ Kp,
    float* __restrict__ scores)
{
    __shared__ float Qs[64][65];
    __shared__ float Ks[64][65];

    const int tid = threadIdx.x;
    const int bh = blockIdx.z;              // b*H + h
    const int b = bh >> 4, h = bh & 15;
    const int q0 = blockIdx.y * 64;
    const int k0 = blockIdx.x * 64;

    const int lr = tid >> 2;                // 0..63
    const int lc = (tid & 3) << 4;          // 0,16,32,48

    const float* qbase = Q  + ((size_t)b * Ssz + q0 + lr) * Dsz + h * HDs + lc;
    const float* kbase = Kp + ((size_t)b * Ssz + k0 + lr) * Dsz + h * HDs + lc;
    #pragma unroll
    for (int i = 0; i < 4; ++i) {
        float4 q4 = *(const float4*)(qbase + i * 4);
        Qs[lr][lc + i * 4 + 0] = q4.x; Qs[lr][lc + i * 4 + 1] = q4.y;
        Qs[lr][lc + i * 4 + 2] = q4.z; Qs[lr][lc + i * 4 + 3] = q4.w;
        float4 k4 = *(const float4*)(kbase + i * 4);
        Ks[lr][lc + i * 4 + 0] = k4.x; Ks[lr][lc + i * 4 + 1] = k4.y;
        Ks[lr][lc + i * 4 + 2] = k4.z; Ks[lr][lc + i * 4 + 3] = k4.w;
    }
    __syncthreads();

    const int tr = tid >> 4, tc = tid & 15;
    float acc[4][4] = {};
    #pragma unroll 8
    for (int d = 0; d < HDs; ++d) {
        float a[4], b[4];
        #pragma unroll
        for (int i = 0; i < 4; ++i) a[i] = Qs[tr * 4 + i][d];
        #pragma unroll
        for (int j = 0; j < 4; ++j) b[j] = Ks[tc * 4 + j][d];
        #pragma unroll
        for (int i = 0; i < 4; ++i)
            #pragma unroll
            for (int j = 0; j < 4; ++j)
                acc[i][j] += a[i] * b[j];
    }

    float* outp = scores + ((size_t)bh * Ssz + q0) * Ssz + k0;
    #pragma unroll
    for (int i = 0; i < 4; ++i)
        #pragma unroll
        for (int j = 0; j < 4; ++j)
            outp[(size_t)(tr * 4 + i) * Ssz + tc * 4 + j] = acc[i][j] * SCALE_F;
}

// ---------------------------------------------------------------------------
// in-place softmax over last dim (S=1024); one block per row, 4 elems/thread
// ---------------------------------------------------------------------------
__global__ __launch_bounds__(256) void softmax_k(float* __restrict__ attn)
{
    const size_t row = blockIdx.x;
    float* p = attn + row * (size_t)Ssz;
    const int t = threadIdx.x;

    float4 v = *(float4*)&p[t << 2];
    float m = fmaxf(fmaxf(v.x, v.y), fmaxf(v.z, v.w));
    #pragma unroll
    for (int off = 1; off < 64; off <<= 1)
        m = fmaxf(m, __shfl_xor(m, off));

    __shared__ float redm[4];
    __shared__ float reds[4];
    const int wave = t >> 6;
    if ((t & 63) == 0) redm[wave] = m;
    __syncthreads();
    m = fmaxf(fmaxf(redm[0], redm[1]), fmaxf(redm[2], redm[3]));

    v.x = __expf(v.x - m); v.y = __expf(v.y - m);
    v.z = __expf(v.z - m); v.w = __expf(v.w - m);
    float s = v.x + v.y + v.z + v.w;
    #pragma unroll
    for (int off = 1; off < 64; off <<= 1)
        s += __shfl_xor(s, off);
    if ((t & 63) == 0) reds[wave] = s;
    __syncthreads();
    s = reds[0] + reds[1] + reds[2] + reds[3];

    const float inv = 1.0f / s;
    v.x *= inv; v.y *= inv; v.z *= inv; v.w *= inv;
    *(float4*)&p[t << 2] = v;
}

// ---------------------------------------------------------------------------
// ctx[b,q,h*64+d] = sum_k attn[b,h,q,k] * V[b,k,h*64+d]
// one block -> 64 q-rows x full 64 d of one (b,h)
// ---------------------------------------------------------------------------
__global__ __launch_bounds__(256) void pv_k(
    const float* __restrict__ attn, const float* __restrict__ V,
    float* __restrict__ ctx)
{
    __shared__ float At[64][65];
    __shared__ float Vt[64][65];

    const int tid = threadIdx.x;
    const int bh = blockIdx.y;
    const int b = bh >> 4, h = bh & 15;
    const int q0 = blockIdx.x * 64;

    const int lr = tid >> 2;
    const int lc = (tid & 3) << 4;
    const int tr = tid >> 4, tc = tid & 15;

    float acc[4][4] = {};

    for (int k0 = 0; k0 < Ssz; k0 += 64) {
        const float* abase = attn + ((size_t)bh * Ssz + q0 + lr) * Ssz + k0 + lc;
        const float* vbase = V + ((size_t)b * Ssz + k0 + lr) * Dsz + h * HDs + lc;
        #pragma unroll
        for (int i = 0; i < 4; ++i) {
            float4 a4 = *(const float4*)(abase + i * 4);
            At[lr][lc + i * 4 + 0] = a4.x; At[lr][lc + i * 4 + 1] = a4.y;
            At[lr][lc + i * 4 + 2] = a4.z; At[lr][lc + i * 4 + 3] = a4.w;
            float4 v4 = *(const float4*)(vbase + i * 4);
            Vt[lr][lc + i * 4 + 0] = v4.x; Vt[lr][lc + i * 4 + 1] = v4.y;
            Vt[lr][lc + i * 4 + 2] = v4.z; Vt[lr][lc + i * 4 + 3] = v4.w;
        }
        __syncthreads();
        #pragma unroll 8
        for (int kk = 0; kk < 64; ++kk) {
            float a[4], b[4];
            #pragma unroll
            for (int i = 0; i < 4; ++i) a[i] = At[tr * 4 + i][kk];
            #pragma unroll
            for (int j = 0; j < 4; ++j) b[j] = Vt[kk][tc * 4 + j];
            #pragma unroll
            for (int i = 0; i < 4; ++i)
                #pragma unroll
                for (int j = 0; j < 4; ++j)
                    acc[i][j] += a[i] * b[j];
        }
        __syncthreads();
    }

    #pragma unroll
    for (int i = 0; i < 4; ++i)
        #pragma unroll
        for (int j = 0; j < 4; ++j)
            ctx[((size_t)b * Ssz + q0 + tr * 4 + i) * Dsz + h * HDs + tc * 4 + j] = acc[i][j];
}

// ---------------------------------------------------------------------------
extern "C" void kernel_launch(void* const* d_in, const int* in_sizes, int n_in,
                              void* d_out, int out_size, void* d_ws, size_t ws_size,
                              hipStream_t stream)
{
    const float* x  = (const float*)d_in[0];
    const float* Wq = (const float*)d_in[1];
    const float* bq = (const float*)d_in[2];
    const float* Wk = (const float*)d_in[3];
    const float* bk = (const float*)d_in[4];
    const float* Wv = (const float*)d_in[5];
    const float* bv = (const float*)d_in[6];
    const float* Wo = (const float*)d_in[7];
    const float* bo = (const float*)d_in[8];

    const size_t BSD = (size_t)Bsz * Ssz * Dsz;     // 16.7M
    float* outp = (float*)d_out;                    // [B,S,D]
    float* attn = outp + BSD;                       // [B,H,S,S]

    float* Q   = (float*)d_ws;                      // 64MB each
    float* K   = Q + BSD;
    float* V   = K + BSD;
    float* ctx = V + BSD;

    dim3 blk(256);
    dim3 gproj(Dsz / 64, (Bsz * Ssz) / 64);         // (16, 256)

    gemm_bias_k<<<gproj, blk, 0, stream>>>(x, Wq, bq, Q, Bsz * Ssz, Dsz, Dsz);
    gemm_bias_k<<<gproj, blk, 0, stream>>>(x, Wk, bk, K, Bsz * Ssz, Dsz, Dsz);
    gemm_bias_k<<<gproj, blk, 0, stream>>>(x, Wv, bv, V, Bsz * Ssz, Dsz, Dsz);

    dim3 gsc(Ssz / 64, Ssz / 64, Bsz * Hn);         // (16,16,256)
    scores_k<<<gsc, blk, 0, stream>>>(Q, K, attn);

    softmax_k<<<dim3((unsigned)((size_t)Bsz * Hn * Ssz)), blk, 0, stream>>>(attn);

    dim3 gpv(Ssz / 64, Bsz * Hn);                   // (16,256)
    pv_k<<<gpv, blk, 0, stream>>>(attn, V, ctx);

    gemm_bias_k<<<gproj, blk, 0, stream>>>(ctx, Wo, bo, outp, Bsz * Ssz, Dsz, Dsz);
}

// Round 2
// 1220.212 us; speedup vs baseline: 2.9380x; 2.9380x over previous
//
#include <hip/hip_runtime.h>
#include <hip/hip_bf16.h>
#include <cstddef>

#define Bsz 16
#define Ssz 1024
#define Dsz 1024
#define Hn  16
#define HDs 64
#define SCALE_F 0.125f

typedef unsigned short ushort_t;
typedef __bf16 bf16x8 __attribute__((ext_vector_type(8)));
typedef float f32x4 __attribute__((ext_vector_type(4)));

#define MFMA16(a, b, c) __builtin_amdgcn_mfma_f32_16x16x32_bf16((a), (b), (c), 0, 0, 0)

__device__ inline ushort_t bf16u(float f) {
    __bf16 h = (__bf16)f;
    return __builtin_bit_cast(ushort_t, h);
}

__device__ inline void gld_lds16(const void* g, void* l) {
    __builtin_amdgcn_global_load_lds(
        (const __attribute__((address_space(1))) unsigned int*)g,
        (__attribute__((address_space(3))) unsigned int*)l, 16, 0, 0);
}

// ---------------------------------------------------------------------------
// cast fp32 -> bf16, 8 elems/thread
// ---------------------------------------------------------------------------
__global__ __launch_bounds__(256) void cast_k(const float* __restrict__ in,
                                              ushort_t* __restrict__ o, size_t n)
{
    size_t i = ((size_t)blockIdx.x * 256 + threadIdx.x) * 8;
    if (i >= n) return;
    float4 a = *(const float4*)(in + i);
    float4 b = *(const float4*)(in + i + 4);
    union { ushort_t u[8]; uint4 v; } pk;
    pk.u[0] = bf16u(a.x); pk.u[1] = bf16u(a.y); pk.u[2] = bf16u(a.z); pk.u[3] = bf16u(a.w);
    pk.u[4] = bf16u(b.x); pk.u[5] = bf16u(b.y); pk.u[6] = bf16u(b.z); pk.u[7] = bf16u(b.w);
    *(uint4*)(o + i) = pk.v;
}

// ---------------------------------------------------------------------------
// W[K,N] fp32 -> Wt[N,K] bf16  (32x32 LDS tile transpose)
// ---------------------------------------------------------------------------
__global__ __launch_bounds__(256) void wtrans_k(const float* __restrict__ W,
                                                ushort_t* __restrict__ Wt)
{
    __shared__ float t_[32][33];
    const int tx = threadIdx.x, ty = threadIdx.y;
    const int n0 = blockIdx.x * 32, k0 = blockIdx.y * 32;
    #pragma unroll
    for (int i = 0; i < 4; ++i)
        t_[ty + i * 8][tx] = W[(size_t)(k0 + ty + i * 8) * Dsz + n0 + tx];
    __syncthreads();
    #pragma unroll
    for (int i = 0; i < 4; ++i)
        Wt[(size_t)(n0 + ty + i * 8) * Dsz + k0 + tx] = bf16u(t_[tx][ty + i * 8]);
}

// ---------------------------------------------------------------------------
// Vbf[B,S,D] bf16 -> Vt[B*H, HD, S] bf16
// ---------------------------------------------------------------------------
__global__ __launch_bounds__(256) void vtrans_k(const ushort_t* __restrict__ V,
                                                ushort_t* __restrict__ Vt)
{
    __shared__ ushort_t t_[32][33];
    const int tx = threadIdx.x, ty = threadIdx.y;
    const int s0 = blockIdx.x * 32, d0 = blockIdx.y * 32, bh = blockIdx.z;
    const int b = bh >> 4, h = bh & 15;
    #pragma unroll
    for (int i = 0; i < 4; ++i)
        t_[ty + i * 8][tx] = V[((size_t)b * Ssz + s0 + ty + i * 8) * Dsz + h * HDs + d0 + tx];
    __syncthreads();
    #pragma unroll
    for (int i = 0; i < 4; ++i)
        Vt[((size_t)bh * HDs + d0 + ty + i * 8) * Ssz + s0 + tx] = t_[tx][ty + i * 8];
}

// ---------------------------------------------------------------------------
// C[M,N] = A[M,K] * Bt[N,K]^T + bias    bf16 MFMA, 128x128 tile, BK=32
// global_load_lds staging with XOR chunk swizzle (both sides).
// ---------------------------------------------------------------------------
template <bool OUT_BF16>
__global__ __launch_bounds__(256) void gemm_bt_k(
    const ushort_t* __restrict__ A, const ushort_t* __restrict__ Bt,
    const float* __restrict__ bias, void* __restrict__ Cout,
    int M, int N, int K)
{
    __shared__ ushort_t As[128 * 32];
    __shared__ ushort_t Bs[128 * 32];

    const int tid = threadIdx.x;
    const int lane = tid & 63;
    const int wv = tid >> 6;
    const int wr = wv >> 1, wc = wv & 1;
    const int bm = blockIdx.y * 128, bn = blockIdx.x * 128;

    // staging: thread t -> LDS bytes [t*16, t*16+16); row=t/4, slot=t%3; global
    // chunk = slot ^ ((row>>1)&3)  (same for rows row and row+64)
    const int srow = tid >> 2;
    const int gc = (tid & 3) ^ ((srow >> 1) & 3);
    const ushort_t* aptr0 = A + (size_t)(bm + srow) * K + gc * 8;
    const ushort_t* aptr1 = A + (size_t)(bm + 64 + srow) * K + gc * 8;
    const ushort_t* bptr0 = Bt + (size_t)(bn + srow) * K + gc * 8;
    const ushort_t* bptr1 = Bt + (size_t)(bn + 64 + srow) * K + gc * 8;
    ushort_t* lA0 = As + tid * 8;
    ushort_t* lA1 = As + 2048 + tid * 8;
    ushort_t* lB0 = Bs + tid * 8;
    ushort_t* lB1 = Bs + 2048 + tid * 8;

    // fragment read mapping
    const int am = lane & 15;
    const int rc = lane >> 4;
    const int aslot = rc ^ ((am >> 1) & 3);   // row-dependent XOR, same for all m
    const int rrow_a = wr * 64 + am;
    const int rrow_b = wc * 64 + am;

    f32x4 acc[4][4] = {};

    for (int k0 = 0; k0 < K; k0 += 32) {
        if (k0) __syncthreads();
        gld_lds16(aptr0, lA0); gld_lds16(aptr1, lA1);
        gld_lds16(bptr0, lB0); gld_lds16(bptr1, lB1);
        aptr0 += 32; aptr1 += 32; bptr0 += 32; bptr1 += 32;
        __syncthreads();

        bf16x8 af[4], bfr[4];
        #pragma unroll
        for (int m = 0; m < 4; ++m)
            af[m] = *reinterpret_cast<const bf16x8*>(&As[(rrow_a + m * 16) * 32 + aslot * 8]);
        #pragma unroll
        for (int n = 0; n < 4; ++n)
            bfr[n] = *reinterpret_cast<const bf16x8*>(&Bs[(rrow_b + n * 16) * 32 + aslot * 8]);
        #pragma unroll
        for (int m = 0; m < 4; ++m)
            #pragma unroll
            for (int n = 0; n < 4; ++n)
                acc[m][n] = MFMA16(af[m], bfr[n], acc[m][n]);
    }

    const int erow = (lane >> 4) * 4;
    #pragma unroll
    for (int m = 0; m < 4; ++m) {
        #pragma unroll
        for (int n = 0; n < 4; ++n) {
            const int col = bn + wc * 64 + n * 16 + am;
            const float bv = bias[col];
            #pragma unroll
            for (int r = 0; r < 4; ++r) {
                const int row = bm + wr * 64 + m * 16 + erow + r;
                const float v = acc[m][n][r] + bv;
                if (OUT_BF16)
                    ((ushort_t*)Cout)[(size_t)row * N + col] = bf16u(v);
                else
                    ((float*)Cout)[(size_t)row * N + col] = v;
            }
        }
    }
}

// ---------------------------------------------------------------------------
// Fused attention: per block = one (b,h), 16 q-rows.
// scores (MFMA) -> P LDS fp32 -> softmax -> attn write -> PV (MFMA) -> ctx bf16
// ---------------------------------------------------------------------------
#define PSTR 1028   // floats per P row (pad: 2-way banks in hot phases)

__global__ __launch_bounds__(256) void attn_fused_k(
    const ushort_t* __restrict__ Qbf, const ushort_t* __restrict__ Kbf,
    const ushort_t* __restrict__ Vt, float* __restrict__ attn,
    ushort_t* __restrict__ ctx)
{
    __shared__ float P[16 * PSTR];
    __shared__ float invbuf[16];

    const int tid = threadIdx.x;
    const int lane = tid & 63;
    const int wv = tid >> 6;
    const int bh = blockIdx.y;
    const int b = bh >> 4, h = bh & 15;
    const int q0 = blockIdx.x * 16;

    const int am = lane & 15;      // frag row/col within 16
    const int ak = lane >> 4;      // k-chunk 0..3

    // ---- phase 1: scores = Q K^T * SCALE, wave wv covers keys [wv*256, +256) ----
    const ushort_t* qptr = Qbf + ((size_t)b * Ssz + q0 + am) * Dsz + h * HDs + ak * 8;
    const bf16x8 qa0 = *reinterpret_cast<const bf16x8*>(qptr);
    const bf16x8 qa1 = *reinterpret_cast<const bf16x8*>(qptr + 32);
    const int kb = wv * 256;
    #pragma unroll 4
    for (int n = 0; n < 16; ++n) {
        const int sk = kb + n * 16 + am;
        const ushort_t* kptr = Kbf + ((size_t)b * Ssz + sk) * Dsz + h * HDs + ak * 8;
        const bf16x8 k0 = *reinterpret_cast<const bf16x8*>(kptr);
        const bf16x8 k1 = *reinterpret_cast<const bf16x8*>(kptr + 32);
        f32x4 acc = {0.f, 0.f, 0.f, 0.f};
        acc = MFMA16(qa0, k0, acc);
        acc = MFMA16(qa1, k1, acc);
        #pragma unroll
        for (int r = 0; r < 4; ++r)
            P[(ak * 4 + r) * PSTR + sk] = acc[r] * SCALE_F;
    }
    __syncthreads();

    // ---- phase 2: softmax over each of 16 rows (16 lanes per row, same wave) ----
    {
        const int row = tid >> 4, lp = tid & 15;
        float* pr = P + row * PSTR;
        float m = -1e30f;
        #pragma unroll 8
        for (int i = 0; i < 64; ++i) m = fmaxf(m, pr[lp + i * 16]);
        m = fmaxf(m, __shfl_xor(m, 1)); m = fmaxf(m, __shfl_xor(m, 2));
        m = fmaxf(m, __shfl_xor(m, 4)); m = fmaxf(m, __shfl_xor(m, 8));
        float s = 0.f;
        #pragma unroll 8
        for (int i = 0; i < 64; ++i) {
            const float e = __expf(pr[lp + i * 16] - m);
            pr[lp + i * 16] = e;
            s += e;
        }
        s += __shfl_xor(s, 1); s += __shfl_xor(s, 2);
        s += __shfl_xor(s, 4); s += __shfl_xor(s, 8);
        if (lp == 0) invbuf[row] = 1.0f / s;
    }
    __syncthreads();

    // ---- phase 3a: write normalized attn (coalesced float4, one row/iter) ----
    {
        float* aout = attn + ((size_t)bh * Ssz + q0) * Ssz;
        #pragma unroll 2
        for (int r = 0; r < 16; ++r) {
            const float inv = invbuf[r];
            float4 v = *(float4*)&P[r * PSTR + tid * 4];
            v.x *= inv; v.y *= inv; v.z *= inv; v.w *= inv;
            *(float4*)&aout[(size_t)r * Ssz + tid * 4] = v;
        }
    }

    // ---- phase 3b: PV. wave wv covers d-range [wv*16, +16) ----
    f32x4 acc = {0.f, 0.f, 0.f, 0.f};
    const int d = wv * 16 + am;
    const ushort_t* vrow = Vt + ((size_t)bh * HDs + d) * Ssz + ak * 8;
    #pragma unroll 2
    for (int ks = 0; ks < 32; ++ks) {
        const int s0 = ks * 32 + ak * 8;
        const float4 p0 = *(float4*)&P[am * PSTR + s0];
        const float4 p1 = *(float4*)&P[am * PSTR + s0 + 4];
        bf16x8 a;
        a[0] = (__bf16)p0.x; a[1] = (__bf16)p0.y; a[2] = (__bf16)p0.z; a[3] = (__bf16)p0.w;
        a[4] = (__bf16)p1.x; a[5] = (__bf16)p1.y; a[6] = (__bf16)p1.z; a[7] = (__bf16)p1.w;
        const bf16x8 bv = *reinterpret_cast<const bf16x8*>(vrow + ks * 32);
        acc = MFMA16(a, bv, acc);
    }
    #pragma unroll
    for (int r = 0; r < 4; ++r) {
        const int row = ak * 4 + r;
        const float v = acc[r] * invbuf[row];
        ctx[((size_t)b * Ssz + q0 + row) * Dsz + h * HDs + wv * 16 + am] = bf16u(v);
    }
}

// ---------------------------------------------------------------------------
extern "C" void kernel_launch(void* const* d_in, const int* in_sizes, int n_in,
                              void* d_out, int out_size, void* d_ws, size_t ws_size,
                              hipStream_t stream)
{
    const float* x  = (const float*)d_in[0];
    const float* Wq = (const float*)d_in[1];
    const float* bq = (const float*)d_in[2];
    const float* Wk = (const float*)d_in[3];
    const float* bk = (const float*)d_in[4];
    const float* Wv = (const float*)d_in[5];
    const float* bv = (const float*)d_in[6];
    const float* Wo = (const float*)d_in[7];
    const float* bo = (const float*)d_in[8];

    const size_t BSD = (size_t)Bsz * Ssz * Dsz;   // 16.7M
    const size_t WSZ = (size_t)Dsz * Dsz;         // 1M

    float* outp = (float*)d_out;                  // [B,S,D] fp32
    float* attn = outp + BSD;                     // [B,H,S,S] fp32

    ushort_t* xbf  = (ushort_t*)d_ws;
    ushort_t* Qbf  = xbf + BSD;
    ushort_t* Kbf  = Qbf + BSD;
    ushort_t* Vbf  = Kbf + BSD;
    ushort_t* Vtb  = Vbf + BSD;
    ushort_t* ctxb = Vtb + BSD;
    ushort_t* Wqt  = ctxb + BSD;
    ushort_t* Wkt  = Wqt + WSZ;
    ushort_t* Wvt  = Wkt + WSZ;
    ushort_t* Wot  = Wvt + WSZ;

    const int M = Bsz * Ssz;                      // 16384

    cast_k<<<dim3((unsigned)(BSD / 2048)), 256, 0, stream>>>(x, xbf, BSD);

    dim3 tblk(32, 8);
    dim3 tgrd(32, 32);
    wtrans_k<<<tgrd, tblk, 0, stream>>>(Wq, Wqt);
    wtrans_k<<<tgrd, tblk, 0, stream>>>(Wk, Wkt);
    wtrans_k<<<tgrd, tblk, 0, stream>>>(Wv, Wvt);
    wtrans_k<<<tgrd, tblk, 0, stream>>>(Wo, Wot);

    dim3 ggrd(Dsz / 128, M / 128);                // (8, 128)
    gemm_bt_k<true><<<ggrd, 256, 0, stream>>>(xbf, Wqt, bq, Qbf, M, Dsz, Dsz);
    gemm_bt_k<true><<<ggrd, 256, 0, stream>>>(xbf, Wkt, bk, Kbf, M, Dsz, Dsz);
    gemm_bt_k<true><<<ggrd, 256, 0, stream>>>(xbf, Wvt, bv, Vbf, M, Dsz, Dsz);

    vtrans_k<<<dim3(Ssz / 32, HDs / 32, Bsz * Hn), tblk, 0, stream>>>(Vbf, Vtb);

    attn_fused_k<<<dim3(Ssz / 16, Bsz * Hn), 256, 0, stream>>>(Qbf, Kbf, Vtb, attn, ctxb);

    gemm_bt_k<false><<<ggrd, 256, 0, stream>>>(ctxb, Wot, bo, outp, M, Dsz, Dsz);
}

// Round 3
// 922.872 us; speedup vs baseline: 3.8846x; 1.3222x over previous
//
#include <hip/hip_runtime.h>
#include <hip/hip_bf16.h>
#include <cstddef>

#define Bsz 16
#define Ssz 1024
#define Dsz 1024
#define Hn  16
#define HDs 64
#define SCALE_F 0.125f

typedef unsigned short ushort_t;
typedef __bf16 bf16x8 __attribute__((ext_vector_type(8)));
typedef float f32x4 __attribute__((ext_vector_type(4)));
typedef ushort_t u16x4 __attribute__((ext_vector_type(4)));

#define MFMA16(a, b, c) __builtin_amdgcn_mfma_f32_16x16x32_bf16((a), (b), (c), 0, 0, 0)

__device__ inline ushort_t bf16u(float f) {
    __bf16 h = (__bf16)f;
    return __builtin_bit_cast(ushort_t, h);
}

__device__ inline void gld_lds16(const void* g, void* l) {
    __builtin_amdgcn_global_load_lds(
        (const __attribute__((address_space(1))) unsigned int*)g,
        (__attribute__((address_space(3))) unsigned int*)l, 16, 0, 0);
}

// ---------------------------------------------------------------------------
// cast fp32 -> bf16, 8 elems/thread
// ---------------------------------------------------------------------------
__global__ __launch_bounds__(256) void cast_k(const float* __restrict__ in,
                                              ushort_t* __restrict__ o, size_t n)
{
    size_t i = ((size_t)blockIdx.x * 256 + threadIdx.x) * 8;
    if (i >= n) return;
    float4 a = *(const float4*)(in + i);
    float4 b = *(const float4*)(in + i + 4);
    union { ushort_t u[8]; uint4 v; } pk;
    pk.u[0] = bf16u(a.x); pk.u[1] = bf16u(a.y); pk.u[2] = bf16u(a.z); pk.u[3] = bf16u(a.w);
    pk.u[4] = bf16u(b.x); pk.u[5] = bf16u(b.y); pk.u[6] = bf16u(b.z); pk.u[7] = bf16u(b.w);
    *(uint4*)(o + i) = pk.v;
}

// ---------------------------------------------------------------------------
// W[K,N] fp32 -> Wt[N,K] bf16  (32x32 LDS tile transpose)
// ---------------------------------------------------------------------------
__global__ __launch_bounds__(256) void wtrans_k(const float* __restrict__ W,
                                                ushort_t* __restrict__ Wt)
{
    __shared__ float t_[32][33];
    const int tx = threadIdx.x, ty = threadIdx.y;
    const int n0 = blockIdx.x * 32, k0 = blockIdx.y * 32;
    #pragma unroll
    for (int i = 0; i < 4; ++i)
        t_[ty + i * 8][tx] = W[(size_t)(k0 + ty + i * 8) * Dsz + n0 + tx];
    __syncthreads();
    #pragma unroll
    for (int i = 0; i < 4; ++i)
        Wt[(size_t)(n0 + ty + i * 8) * Dsz + k0 + tx] = bf16u(t_[tx][ty + i * 8]);
}

// ---------------------------------------------------------------------------
// Vbf[B,S,D] bf16 -> Vt[B*H, HD, S] bf16
// ---------------------------------------------------------------------------
__global__ __launch_bounds__(256) void vtrans_k(const ushort_t* __restrict__ V,
                                                ushort_t* __restrict__ Vt)
{
    __shared__ ushort_t t_[32][33];
    const int tx = threadIdx.x, ty = threadIdx.y;
    const int s0 = blockIdx.x * 32, d0 = blockIdx.y * 32, bh = blockIdx.z;
    const int b = bh >> 4, h = bh & 15;
    #pragma unroll
    for (int i = 0; i < 4; ++i)
        t_[ty + i * 8][tx] = V[((size_t)b * Ssz + s0 + ty + i * 8) * Dsz + h * HDs + d0 + tx];
    __syncthreads();
    #pragma unroll
    for (int i = 0; i < 4; ++i)
        Vt[((size_t)bh * HDs + d0 + ty + i * 8) * Ssz + s0 + tx] = t_[tx][ty + i * 8];
}

// ---------------------------------------------------------------------------
// C[M,N] = A[M,K] * Bt[N,K]^T + bias    bf16 MFMA, 128x128 tile, BK=32
// ---------------------------------------------------------------------------
template <bool OUT_BF16>
__global__ __launch_bounds__(256) void gemm_bt_k(
    const ushort_t* __restrict__ A, const ushort_t* __restrict__ Bt,
    const float* __restrict__ bias, void* __restrict__ Cout,
    int M, int N, int K)
{
    __shared__ ushort_t As[128 * 32];
    __shared__ ushort_t Bs[128 * 32];

    const int tid = threadIdx.x;
    const int lane = tid & 63;
    const int wv = tid >> 6;
    const int wr = wv >> 1, wc = wv & 1;
    const int bm = blockIdx.y * 128, bn = blockIdx.x * 128;

    const int srow = tid >> 2;
    const int gc = (tid & 3) ^ ((srow >> 1) & 3);
    const ushort_t* aptr0 = A + (size_t)(bm + srow) * K + gc * 8;
    const ushort_t* aptr1 = A + (size_t)(bm + 64 + srow) * K + gc * 8;
    const ushort_t* bptr0 = Bt + (size_t)(bn + srow) * K + gc * 8;
    const ushort_t* bptr1 = Bt + (size_t)(bn + 64 + srow) * K + gc * 8;
    ushort_t* lA0 = As + tid * 8;
    ushort_t* lA1 = As + 2048 + tid * 8;
    ushort_t* lB0 = Bs + tid * 8;
    ushort_t* lB1 = Bs + 2048 + tid * 8;

    const int am = lane & 15;
    const int rc = lane >> 4;
    const int aslot = rc ^ ((am >> 1) & 3);
    const int rrow_a = wr * 64 + am;
    const int rrow_b = wc * 64 + am;

    f32x4 acc[4][4] = {};

    for (int k0 = 0; k0 < K; k0 += 32) {
        if (k0) __syncthreads();
        gld_lds16(aptr0, lA0); gld_lds16(aptr1, lA1);
        gld_lds16(bptr0, lB0); gld_lds16(bptr1, lB1);
        aptr0 += 32; aptr1 += 32; bptr0 += 32; bptr1 += 32;
        __syncthreads();

        bf16x8 af[4], bfr[4];
        #pragma unroll
        for (int m = 0; m < 4; ++m)
            af[m] = *reinterpret_cast<const bf16x8*>(&As[(rrow_a + m * 16) * 32 + aslot * 8]);
        #pragma unroll
        for (int n = 0; n < 4; ++n)
            bfr[n] = *reinterpret_cast<const bf16x8*>(&Bs[(rrow_b + n * 16) * 32 + aslot * 8]);
        #pragma unroll
        for (int m = 0; m < 4; ++m)
            #pragma unroll
            for (int n = 0; n < 4; ++n)
                acc[m][n] = MFMA16(af[m], bfr[n], acc[m][n]);
    }

    const int erow = (lane >> 4) * 4;
    #pragma unroll
    for (int m = 0; m < 4; ++m) {
        #pragma unroll
        for (int n = 0; n < 4; ++n) {
            const int col = bn + wc * 64 + n * 16 + am;
            const float bv = bias[col];
            #pragma unroll
            for (int r = 0; r < 4; ++r) {
                const int row = bm + wr * 64 + m * 16 + erow + r;
                const float v = acc[m][n][r] + bv;
                if (OUT_BF16)
                    ((ushort_t*)Cout)[(size_t)row * N + col] = bf16u(v);
                else
                    ((float*)Cout)[(size_t)row * N + col] = v;
            }
        }
    }
}

// ---------------------------------------------------------------------------
// Fused attention v2: swapped QK^T (P in registers), reg softmax, attn write
// from regs, bf16 P -> LDS (XOR swizzle) -> PV MFMA.
// Block = 256 thr = 4 waves, one (b,h), 16 q-rows. Wave wv: keys [wv*256,+256).
// Lane (am = lane&15, ak = lane>>4): phase1 C col q=am, row key = ak*4+r.
// ---------------------------------------------------------------------------
__global__ __launch_bounds__(256, 4) void attn_fused_k(
    const ushort_t* __restrict__ Qbf, const ushort_t* __restrict__ Kbf,
    const ushort_t* __restrict__ Vt, float* __restrict__ attn,
    ushort_t* __restrict__ ctx)
{
    __shared__ ushort_t Pl[16 * 1024];   // [q][k] bf16, byte^=(q&7)<<4 swizzle
    __shared__ float smax[4][16];
    __shared__ float ssum[4][16];
    __shared__ float invb[16];

    const int tid = threadIdx.x;
    const int lane = tid & 63;
    const int wv = tid >> 6;
    const int am = lane & 15;
    const int ak = lane >> 4;
    const int bh = blockIdx.y;
    const int b = bh >> 4, h = bh & 15;
    const int q0 = blockIdx.x * 16;
    const int kb = wv * 256;

    // ---- phase 1: scores^T via mfma(K, Q); lane holds q=am, 64 keys ----
    const ushort_t* qptr = Qbf + ((size_t)b * Ssz + q0 + am) * Dsz + h * HDs + ak * 8;
    const bf16x8 qf0 = *(const bf16x8*)qptr;
    const bf16x8 qf1 = *(const bf16x8*)(qptr + 32);

    f32x4 acc[16];
    #pragma unroll
    for (int n = 0; n < 16; ++n) acc[n] = (f32x4){0.f, 0.f, 0.f, 0.f};

    const ushort_t* kbase = Kbf + ((size_t)b * Ssz + kb + am) * Dsz + h * HDs + ak * 8;
    #pragma unroll
    for (int n = 0; n < 16; ++n) {
        const ushort_t* kp = kbase + (size_t)n * 16 * Dsz;
        const bf16x8 kf0 = *(const bf16x8*)kp;
        const bf16x8 kf1 = *(const bf16x8*)(kp + 32);
        acc[n] = MFMA16(kf0, qf0, acc[n]);
        acc[n] = MFMA16(kf1, qf1, acc[n]);
    }

    // ---- phase 2: softmax stats in-register ----
    float m = -1e30f;
    #pragma unroll
    for (int n = 0; n < 16; ++n)
        #pragma unroll
        for (int r = 0; r < 4; ++r) m = fmaxf(m, acc[n][r]);
    m = fmaxf(m, __shfl_xor(m, 16));
    m = fmaxf(m, __shfl_xor(m, 32));
    if (ak == 0) smax[wv][am] = m;
    __syncthreads();
    m = fmaxf(fmaxf(smax[0][am], smax[1][am]), fmaxf(smax[2][am], smax[3][am]));

    float s = 0.f;
    #pragma unroll
    for (int n = 0; n < 16; ++n)
        #pragma unroll
        for (int r = 0; r < 4; ++r) {
            const float e = __expf((acc[n][r] - m) * SCALE_F);
            acc[n][r] = e;
            s += e;
        }
    s += __shfl_xor(s, 16);
    s += __shfl_xor(s, 32);
    if (ak == 0) ssum[wv][am] = s;

    // ---- phase 3a: P (unnormalized e) -> LDS bf16, swizzled ----
    char* prow = (char*)Pl + am * 2048;
    const int xr = (am & 7) << 4;
    #pragma unroll
    for (int n = 0; n < 16; ++n) {
        u16x4 pk;
        pk.x = bf16u(acc[n][0]); pk.y = bf16u(acc[n][1]);
        pk.z = bf16u(acc[n][2]); pk.w = bf16u(acc[n][3]);
        *(u16x4*)(prow + (((kb + n * 16 + ak * 4) * 2) ^ xr)) = pk;
    }
    __syncthreads();

    const float inv = 1.0f / (ssum[0][am] + ssum[1][am] + ssum[2][am] + ssum[3][am]);
    if (wv == 0 && ak == 0) invb[am] = inv;

    // ---- phase 3b: write normalized attn from registers ----
    float* aout = attn + ((size_t)bh * Ssz + q0 + am) * Ssz + kb + ak * 4;
    #pragma unroll
    for (int n = 0; n < 16; ++n) {
        float4 v;
        v.x = acc[n][0] * inv; v.y = acc[n][1] * inv;
        v.z = acc[n][2] * inv; v.w = acc[n][3] * inv;
        *(float4*)(aout + n * 16) = v;
    }
    __syncthreads();

    // ---- phase 4: PV. wave wv -> d slice [wv*16,+16); C row q=ak*4+r, col d=am ----
    f32x4 po = {0.f, 0.f, 0.f, 0.f};
    const ushort_t* vrow = Vt + ((size_t)bh * HDs + wv * 16 + am) * Ssz;
    #pragma unroll 4
    for (int w = 0; w < 32; ++w) {
        const bf16x8 pf = *(const bf16x8*)(prow + ((w * 64 + ak * 16) ^ xr));
        const bf16x8 vf = *(const bf16x8*)(vrow + w * 32 + ak * 8);
        po = MFMA16(pf, vf, po);
    }
    #pragma unroll
    for (int r = 0; r < 4; ++r) {
        const float v = po[r] * invb[ak * 4 + r];
        ctx[((size_t)b * Ssz + q0 + ak * 4 + r) * Dsz + h * HDs + wv * 16 + am] = bf16u(v);
    }
}

// ---------------------------------------------------------------------------
extern "C" void kernel_launch(void* const* d_in, const int* in_sizes, int n_in,
                              void* d_out, int out_size, void* d_ws, size_t ws_size,
                              hipStream_t stream)
{
    const float* x  = (const float*)d_in[0];
    const float* Wq = (const float*)d_in[1];
    const float* bq = (const float*)d_in[2];
    const float* Wk = (const float*)d_in[3];
    const float* bk = (const float*)d_in[4];
    const float* Wv = (const float*)d_in[5];
    const float* bv = (const float*)d_in[6];
    const float* Wo = (const float*)d_in[7];
    const float* bo = (const float*)d_in[8];

    const size_t BSD = (size_t)Bsz * Ssz * Dsz;   // 16.7M
    const size_t WSZ = (size_t)Dsz * Dsz;         // 1M

    float* outp = (float*)d_out;                  // [B,S,D] fp32
    float* attn = outp + BSD;                     // [B,H,S,S] fp32

    ushort_t* xbf  = (ushort_t*)d_ws;
    ushort_t* Qbf  = xbf + BSD;
    ushort_t* Kbf  = Qbf + BSD;
    ushort_t* Vbf  = Kbf + BSD;
    ushort_t* Vtb  = Vbf + BSD;
    ushort_t* ctxb = Vtb + BSD;
    ushort_t* Wqt  = ctxb + BSD;
    ushort_t* Wkt  = Wqt + WSZ;
    ushort_t* Wvt  = Wkt + WSZ;
    ushort_t* Wot  = Wvt + WSZ;

    const int M = Bsz * Ssz;                      // 16384

    cast_k<<<dim3((unsigned)(BSD / 2048)), 256, 0, stream>>>(x, xbf, BSD);

    dim3 tblk(32, 8);
    dim3 tgrd(32, 32);
    wtrans_k<<<tgrd, tblk, 0, stream>>>(Wq, Wqt);
    wtrans_k<<<tgrd, tblk, 0, stream>>>(Wk, Wkt);
    wtrans_k<<<tgrd, tblk, 0, stream>>>(Wv, Wvt);
    wtrans_k<<<tgrd, tblk, 0, stream>>>(Wo, Wot);

    dim3 ggrd(Dsz / 128, M / 128);                // (8, 128)
    gemm_bt_k<true><<<ggrd, 256, 0, stream>>>(xbf, Wqt, bq, Qbf, M, Dsz, Dsz);
    gemm_bt_k<true><<<ggrd, 256, 0, stream>>>(xbf, Wkt, bk, Kbf, M, Dsz, Dsz);
    gemm_bt_k<true><<<ggrd, 256, 0, stream>>>(xbf, Wvt, bv, Vbf, M, Dsz, Dsz);

    vtrans_k<<<dim3(Ssz / 32, HDs / 32, Bsz * Hn), tblk, 0, stream>>>(Vbf, Vtb);

    attn_fused_k<<<dim3(Ssz / 16, Bsz * Hn), 256, 0, stream>>>(Qbf, Kbf, Vtb, attn, ctxb);

    gemm_bt_k<false><<<ggrd, 256, 0, stream>>>(ctxb, Wot, bo, outp, M, Dsz, Dsz);
}

// Round 4
// 740.949 us; speedup vs baseline: 4.8383x; 1.2455x over previous
//
#include <hip/hip_runtime.h>
#include <hip/hip_bf16.h>
#include <cstddef>

#define Bsz 16
#define Ssz 1024
#define Dsz 1024
#define Hn  16
#define HDs 64
#define SCALE_F 0.125f

typedef unsigned short ushort_t;
typedef __bf16 bf16x8 __attribute__((ext_vector_type(8)));
typedef float f32x4 __attribute__((ext_vector_type(4)));
typedef ushort_t u16x4 __attribute__((ext_vector_type(4)));

#define MFMA16(a, b, c) __builtin_amdgcn_mfma_f32_16x16x32_bf16((a), (b), (c), 0, 0, 0)

__device__ inline ushort_t bf16u(float f) {
    __bf16 h = (__bf16)f;
    return __builtin_bit_cast(ushort_t, h);
}

__device__ inline void gld_lds16(const void* g, void* l) {
    __builtin_amdgcn_global_load_lds(
        (const __attribute__((address_space(1))) unsigned int*)g,
        (__attribute__((address_space(3))) unsigned int*)l, 16, 0, 0);
}

// ---------------------------------------------------------------------------
// cast fp32 -> bf16, 8 elems/thread
// ---------------------------------------------------------------------------
__global__ __launch_bounds__(256) void cast_k(const float* __restrict__ in,
                                              ushort_t* __restrict__ o, size_t n)
{
    size_t i = ((size_t)blockIdx.x * 256 + threadIdx.x) * 8;
    if (i >= n) return;
    float4 a = *(const float4*)(in + i);
    float4 b = *(const float4*)(in + i + 4);
    union { ushort_t u[8]; uint4 v; } pk;
    pk.u[0] = bf16u(a.x); pk.u[1] = bf16u(a.y); pk.u[2] = bf16u(a.z); pk.u[3] = bf16u(a.w);
    pk.u[4] = bf16u(b.x); pk.u[5] = bf16u(b.y); pk.u[6] = bf16u(b.z); pk.u[7] = bf16u(b.w);
    *(uint4*)(o + i) = pk.v;
}

// ---------------------------------------------------------------------------
// W[K,N] fp32 -> Wt[N,K] bf16  (32x32 LDS tile transpose)
// ---------------------------------------------------------------------------
__global__ __launch_bounds__(256) void wtrans_k(const float* __restrict__ W,
                                                ushort_t* __restrict__ Wt)
{
    __shared__ float t_[32][33];
    const int tx = threadIdx.x, ty = threadIdx.y;
    const int n0 = blockIdx.x * 32, k0 = blockIdx.y * 32;
    #pragma unroll
    for (int i = 0; i < 4; ++i)
        t_[ty + i * 8][tx] = W[(size_t)(k0 + ty + i * 8) * Dsz + n0 + tx];
    __syncthreads();
    #pragma unroll
    for (int i = 0; i < 4; ++i)
        Wt[(size_t)(n0 + ty + i * 8) * Dsz + k0 + tx] = bf16u(t_[tx][ty + i * 8]);
}

// ---------------------------------------------------------------------------
// C = A[M,K] * Bt[N,K]^T + bias.  bf16 MFMA, 128x128 tile, BK=32.
// MODE 0: fp32 out [M,N] (final projection)
// MODE 1: fused QKV; N=3072; block-uniform tsel = bn>>10 selects target:
//   Q -> Qh[bh][s][64]
//   K -> Kp[bh][s>>4][d>>5][lane=((d>>3)&3)*16+(s&15)][d&7]   (1KB lane-packed)
//   V -> Vp[bh][d>>4][s>>5][lane=((s>>3)&3)*16+(d&15)][s&7]   (1KB lane-packed)
// ---------------------------------------------------------------------------
template <int MODE>
__global__ __launch_bounds__(256) void gemm_bt_k(
    const ushort_t* __restrict__ A, const ushort_t* __restrict__ Bt,
    const float* __restrict__ b0, const float* __restrict__ b1,
    const float* __restrict__ b2,
    void* __restrict__ o0, void* __restrict__ o1, void* __restrict__ o2,
    int M, int N, int K)
{
    __shared__ ushort_t As[128 * 32];
    __shared__ ushort_t Bs[128 * 32];

    const int tid = threadIdx.x;
    const int lane = tid & 63;
    const int wv = tid >> 6;
    const int wr = wv >> 1, wc = wv & 1;
    const int bm = blockIdx.y * 128, bn = blockIdx.x * 128;

    const int srw = tid >> 2;
    const int gc = (tid & 3) ^ ((srw >> 1) & 3);
    const ushort_t* aptr0 = A + (size_t)(bm + srw) * K + gc * 8;
    const ushort_t* aptr1 = A + (size_t)(bm + 64 + srw) * K + gc * 8;
    const ushort_t* bptr0 = Bt + (size_t)(bn + srw) * K + gc * 8;
    const ushort_t* bptr1 = Bt + (size_t)(bn + 64 + srw) * K + gc * 8;
    ushort_t* lA0 = As + tid * 8;
    ushort_t* lA1 = As + 2048 + tid * 8;
    ushort_t* lB0 = Bs + tid * 8;
    ushort_t* lB1 = Bs + 2048 + tid * 8;

    const int am = lane & 15;
    const int rc = lane >> 4;
    const int aslot = rc ^ ((am >> 1) & 3);
    const int rrow_a = wr * 64 + am;
    const int rrow_b = wc * 64 + am;

    f32x4 acc[4][4] = {};

    for (int k0 = 0; k0 < K; k0 += 32) {
        if (k0) __syncthreads();
        gld_lds16(aptr0, lA0); gld_lds16(aptr1, lA1);
        gld_lds16(bptr0, lB0); gld_lds16(bptr1, lB1);
        aptr0 += 32; aptr1 += 32; bptr0 += 32; bptr1 += 32;
        __syncthreads();

        bf16x8 af[4], bfr[4];
        #pragma unroll
        for (int m = 0; m < 4; ++m)
            af[m] = *reinterpret_cast<const bf16x8*>(&As[(rrow_a + m * 16) * 32 + aslot * 8]);
        #pragma unroll
        for (int n = 0; n < 4; ++n)
            bfr[n] = *reinterpret_cast<const bf16x8*>(&Bs[(rrow_b + n * 16) * 32 + aslot * 8]);
        #pragma unroll
        for (int m = 0; m < 4; ++m)
            #pragma unroll
            for (int n = 0; n < 4; ++n)
                acc[m][n] = MFMA16(af[m], bfr[n], acc[m][n]);
    }

    const int erow = rc * 4;

    if constexpr (MODE == 0) {
        float* C = (float*)o0;
        #pragma unroll
        for (int m = 0; m < 4; ++m) {
            #pragma unroll
            for (int n = 0; n < 4; ++n) {
                const int col = bn + wc * 64 + n * 16 + am;
                const float bv = b0[col];
                #pragma unroll
                for (int r = 0; r < 4; ++r) {
                    const int row = bm + wr * 64 + m * 16 + erow + r;
                    C[(size_t)row * N + col] = acc[m][n][r] + bv;
                }
            }
        }
    } else {
        const int tsel = bn >> 10;    // block-uniform (1024 % 128 == 0)
        const float* bias = (tsel == 0) ? b0 : (tsel == 1) ? b1 : b2;
        ushort_t* dst = (ushort_t*)((tsel == 0) ? o0 : (tsel == 1) ? o1 : o2);
        #pragma unroll
        for (int m = 0; m < 4; ++m) {
            const int row0 = bm + wr * 64 + m * 16 + erow;   // +r
            const int b_ = row0 >> 10;
            const int srow0 = row0 & 1023;
            #pragma unroll
            for (int n = 0; n < 4; ++n) {
                const int col = bn + wc * 64 + n * 16 + am;
                const int c1 = col & 1023;
                const int h = c1 >> 6, d = c1 & 63;
                const float bv = bias[c1];
                const size_t hb = ((size_t)(b_ * 16 + h)) << 16;   // *65536
                if (tsel == 0) {
                    // Qh[bh][s][64]
                    #pragma unroll
                    for (int r = 0; r < 4; ++r)
                        dst[hb + (size_t)(srow0 + r) * 64 + d] =
                            bf16u(acc[m][n][r] + bv);
                } else if (tsel == 1) {
                    // Kp: [s>>4][d>>5][((d>>3)&3)*16 + (s&15)][d&7]
                    const size_t base = hb + (size_t)(srow0 >> 4) * 1024
                                      + (d >> 5) * 512
                                      + (((d >> 3) & 3) * 16 + (srow0 & 15)) * 8
                                      + (d & 7);
                    #pragma unroll
                    for (int r = 0; r < 4; ++r)
                        dst[base + r * 8] = bf16u(acc[m][n][r] + bv);
                } else {
                    // Vp: [d>>4][s>>5][((s>>3)&3)*16 + (d&15)][s&7]; 4 consecutive s
                    const size_t base = hb + (size_t)(d >> 4) * 16384
                                      + (srow0 >> 5) * 512
                                      + (((srow0 >> 3) & 3) * 16 + (d & 15)) * 8
                                      + (srow0 & 7);
                    u16x4 pk;
                    pk.x = bf16u(acc[m][n][0] + bv);
                    pk.y = bf16u(acc[m][n][1] + bv);
                    pk.z = bf16u(acc[m][n][2] + bv);
                    pk.w = bf16u(acc[m][n][3] + bv);
                    *(u16x4*)&dst[base] = pk;
                }
            }
        }
    }
}

// ---------------------------------------------------------------------------
// Fused attention v3: packed-layout loads (all 1KB wave-contiguous), swapped
// QK^T (P in regs), reg softmax, attn write from regs, bf16 P -> LDS (XOR
// swizzle) -> PV MFMA. 1D grid 16384 with bijective XCD swizzle so each
// head's 64 q-blocks stay on one XCD's L2.
// ---------------------------------------------------------------------------
__global__ __launch_bounds__(256, 4) void attn_fused_k(
    const ushort_t* __restrict__ Qh, const ushort_t* __restrict__ Kp,
    const ushort_t* __restrict__ Vp, float* __restrict__ attn,
    ushort_t* __restrict__ ctx)
{
    __shared__ ushort_t Pl[16 * 1024];   // [q][k] bf16, byte^=(q&7)<<4 swizzle
    __shared__ float smax[4][16];
    __shared__ float ssum[4][16];
    __shared__ float invb[16];

    const int tid = threadIdx.x;
    const int lane = tid & 63;
    const int wv = tid >> 6;
    const int am = lane & 15;
    const int ak = lane >> 4;

    const int wg = blockIdx.x;                    // 16384 blocks
    const int swz = (wg & 7) * 2048 + (wg >> 3);  // bijective XCD swizzle
    const int bh = swz >> 6;
    const int q0 = (swz & 63) << 4;
    const int b = bh >> 4, h = bh & 15;
    const size_t hb = (size_t)bh << 16;           // *65536
    const int kb = wv * 256;

    // ---- phase 1: scores^T via mfma(K, Q); lane holds q=am, 64 keys ----
    const ushort_t* qptr = Qh + hb + (size_t)(q0 + am) * 64 + ak * 8;
    const bf16x8 qf0 = *(const bf16x8*)qptr;
    const bf16x8 qf1 = *(const bf16x8*)(qptr + 32);

    f32x4 acc[16];
    #pragma unroll
    for (int n = 0; n < 16; ++n) acc[n] = (f32x4){0.f, 0.f, 0.f, 0.f};

    const ushort_t* kt = Kp + hb + (size_t)(wv * 16) * 1024 + lane * 8;
    __builtin_amdgcn_s_setprio(1);
    #pragma unroll
    for (int n = 0; n < 16; ++n) {
        const bf16x8 kf0 = *(const bf16x8*)(kt + n * 1024);
        const bf16x8 kf1 = *(const bf16x8*)(kt + n * 1024 + 512);
        acc[n] = MFMA16(kf0, qf0, acc[n]);
        acc[n] = MFMA16(kf1, qf1, acc[n]);
    }
    __builtin_amdgcn_s_setprio(0);

    // ---- phase 2: softmax stats in-register ----
    float m = -1e30f;
    #pragma unroll
    for (int n = 0; n < 16; ++n)
        #pragma unroll
        for (int r = 0; r < 4; ++r) m = fmaxf(m, acc[n][r]);
    m = fmaxf(m, __shfl_xor(m, 16));
    m = fmaxf(m, __shfl_xor(m, 32));
    if (ak == 0) smax[wv][am] = m;
    __syncthreads();
    m = fmaxf(fmaxf(smax[0][am], smax[1][am]), fmaxf(smax[2][am], smax[3][am]));

    float s = 0.f;
    #pragma unroll
    for (int n = 0; n < 16; ++n)
        #pragma unroll
        for (int r = 0; r < 4; ++r) {
            const float e = __expf((acc[n][r] - m) * SCALE_F);
            acc[n][r] = e;
            s += e;
        }
    s += __shfl_xor(s, 16);
    s += __shfl_xor(s, 32);
    if (ak == 0) ssum[wv][am] = s;

    // ---- phase 3a: P (unnormalized e) -> LDS bf16, swizzled ----
    char* prow = (char*)Pl + am * 2048;
    const int xr = (am & 7) << 4;
    #pragma unroll
    for (int n = 0; n < 16; ++n) {
        u16x4 pk;
        pk.x = bf16u(acc[n][0]); pk.y = bf16u(acc[n][1]);
        pk.z = bf16u(acc[n][2]); pk.w = bf16u(acc[n][3]);
        *(u16x4*)(prow + (((kb + n * 16 + ak * 4) * 2) ^ xr)) = pk;
    }
    __syncthreads();

    const float inv = 1.0f / (ssum[0][am] + ssum[1][am] + ssum[2][am] + ssum[3][am]);
    if (wv == 0 && ak == 0) invb[am] = inv;

    // ---- phase 3b: write normalized attn from registers ----
    float* aout = attn + ((size_t)bh * Ssz + q0 + am) * Ssz + kb + ak * 4;
    #pragma unroll
    for (int n = 0; n < 16; ++n) {
        float4 v;
        v.x = acc[n][0] * inv; v.y = acc[n][1] * inv;
        v.z = acc[n][2] * inv; v.w = acc[n][3] * inv;
        *(float4*)(aout + n * 16) = v;
    }
    __syncthreads();

    // ---- phase 4: PV. wave wv -> d slice [wv*16,+16); C row q=ak*4+r, col d=am ----
    f32x4 po = {0.f, 0.f, 0.f, 0.f};
    const ushort_t* vt = Vp + hb + (size_t)wv * 16384 + lane * 8;
    __builtin_amdgcn_s_setprio(1);
    #pragma unroll 8
    for (int w = 0; w < 32; ++w) {
        const bf16x8 pf = *(const bf16x8*)(prow + ((w * 64 + ak * 16) ^ xr));
        const bf16x8 vf = *(const bf16x8*)(vt + w * 512);
        po = MFMA16(pf, vf, po);
    }
    __builtin_amdgcn_s_setprio(0);
    #pragma unroll
    for (int r = 0; r < 4; ++r) {
        const float v = po[r] * invb[ak * 4 + r];
        ctx[((size_t)b * Ssz + q0 + ak * 4 + r) * Dsz + h * HDs + wv * 16 + am] = bf16u(v);
    }
}

// ---------------------------------------------------------------------------
extern "C" void kernel_launch(void* const* d_in, const int* in_sizes, int n_in,
                              void* d_out, int out_size, void* d_ws, size_t ws_size,
                              hipStream_t stream)
{
    const float* x  = (const float*)d_in[0];
    const float* Wq = (const float*)d_in[1];
    const float* bq = (const float*)d_in[2];
    const float* Wk = (const float*)d_in[3];
    const float* bk = (const float*)d_in[4];
    const float* Wv = (const float*)d_in[5];
    const float* bv = (const float*)d_in[6];
    const float* Wo = (const float*)d_in[7];
    const float* bo = (const float*)d_in[8];

    const size_t BSD = (size_t)Bsz * Ssz * Dsz;   // 16.7M
    const size_t WSZ = (size_t)Dsz * Dsz;         // 1M

    float* outp = (float*)d_out;                  // [B,S,D] fp32
    float* attn = outp + BSD;                     // [B,H,S,S] fp32

    ushort_t* xbf  = (ushort_t*)d_ws;
    ushort_t* Qh   = xbf + BSD;
    ushort_t* Kp   = Qh + BSD;
    ushort_t* Vp   = Kp + BSD;
    ushort_t* ctxb = Vp + BSD;
    ushort_t* Wqkv = ctxb + BSD;                  // [3072][1024] = Wq^T|Wk^T|Wv^T
    ushort_t* Wot  = Wqkv + 3 * WSZ;

    const int M = Bsz * Ssz;                      // 16384

    cast_k<<<dim3((unsigned)(BSD / 2048)), 256, 0, stream>>>(x, xbf, BSD);

    dim3 tblk(32, 8);
    dim3 tgrd(32, 32);
    wtrans_k<<<tgrd, tblk, 0, stream>>>(Wq, Wqkv);
    wtrans_k<<<tgrd, tblk, 0, stream>>>(Wk, Wqkv + WSZ);
    wtrans_k<<<tgrd, tblk, 0, stream>>>(Wv, Wqkv + 2 * WSZ);
    wtrans_k<<<tgrd, tblk, 0, stream>>>(Wo, Wot);

    // fused QKV GEMM: N=3072
    gemm_bt_k<1><<<dim3(24, 128), 256, 0, stream>>>(
        xbf, Wqkv, bq, bk, bv, Qh, Kp, Vp, M, 3072, Dsz);

    attn_fused_k<<<dim3(16384), 256, 0, stream>>>(Qh, Kp, Vp, attn, ctxb);

    gemm_bt_k<0><<<dim3(8, 128), 256, 0, stream>>>(
        ctxb, Wot, bo, nullptr, nullptr, outp, nullptr, nullptr, M, Dsz, Dsz);
}